// Round 1
// baseline (208.568 us; speedup 1.0000x reference)
//
#include <hip/hip_runtime.h>
#include <math.h>

#define NUM_TASKS 16
#define B_ROWS    8192
#define BM        128
#define BN        128
#define BK        64
#define MAX_TILES (B_ROWS / BM + NUM_TASKS)   // 80

typedef __attribute__((ext_vector_type(4))) float f32x4;
typedef __attribute__((ext_vector_type(8))) short bf16x8;

__device__ inline short f2bf(float f) {
    union { float f; unsigned u; } c; c.f = f;
    unsigned u = c.u;
    unsigned r = (u + 0x7FFFu + ((u >> 16) & 1u)) >> 16;
    return (short)r;
}

// ---------------------------------------------------------------------------
// Bucket kernel: deterministic (stable) counting sort of rows by task.
// Single block, 256 threads, each owns 32 consecutive rows.
// Emits: sidx[8192] (sorted row ids), padded tile list (rowbase, task, rowend).
// ---------------------------------------------------------------------------
__global__ __launch_bounds__(256) void bucket_kernel(
    const int* __restrict__ task_ids,
    int* __restrict__ sidx,
    int* __restrict__ tile_base,
    int* __restrict__ tile_task,
    int* __restrict__ tile_end,
    int* __restrict__ ntiles)
{
    __shared__ int cnt[256][NUM_TASKS];   // 16 KB
    __shared__ int offs[NUM_TASKS + 1];
    __shared__ int tot[NUM_TASKS];

    const int tid = threadIdx.x;
    #pragma unroll
    for (int t = 0; t < NUM_TASKS; ++t) cnt[tid][t] = 0;
    const int base = tid * (B_ROWS / 256);   // 32 rows per thread

    for (int i = 0; i < B_ROWS / 256; ++i) {
        int t = task_ids[base + i];
        cnt[tid][t]++;
    }
    __syncthreads();

    // exclusive prefix across the 256 chunks, per task (16 threads)
    if (tid < NUM_TASKS) {
        int s = 0;
        for (int c = 0; c < 256; ++c) { int v = cnt[c][tid]; cnt[c][tid] = s; s += v; }
        tot[tid] = s;
    }
    __syncthreads();

    if (tid == 0) {
        int s = 0;
        for (int t = 0; t < NUM_TASKS; ++t) { offs[t] = s; s += tot[t]; }
        offs[NUM_TASKS] = s;   // == 8192
        int nt = 0;
        for (int t = 0; t < NUM_TASKS; ++t) {
            for (int r = offs[t]; r < offs[t + 1]; r += BM) {
                tile_base[nt] = r;
                tile_task[nt] = t;
                tile_end[nt]  = offs[t + 1];
                nt++;
            }
        }
        *ntiles = nt;
    }
    __syncthreads();

    // stable scatter: each thread places its 32 rows in order
    for (int i = 0; i < B_ROWS / 256; ++i) {
        int row = base + i;
        int t = task_ids[row];
        int pos = offs[t] + cnt[tid][t];
        cnt[tid][t] = cnt[tid][t] + 1;   // owning thread only, no race
        sidx[pos] = row;
    }
}

// ---------------------------------------------------------------------------
// Grouped GEMM layer kernel.
//   IN_BF16  = 0 : input is fp32, rows gathered via sidx (layer 0 reads x)
//   IN_BF16  = 1 : input is bf16, rows already sorted-contiguous (H0/H1)
//   OUT_FINAL= 0 : out = bf16 tanh(acc + bias), stored sorted (hidden layers)
//   OUT_FINAL= 1 : out = fp32 (acc + bias), scattered via sidx (final layer)
// Block: 256 threads = 4 waves (2x2), tile BM=128 x BN=128, K-step BK=64.
// MFMA 16x16x32 bf16; LDS tiles XOR-swizzled ((row&7)<<3 on 8-short chunks)
// to kill the 16-way bank conflict of the 128-B row stride.
// ---------------------------------------------------------------------------
template<int K, int N, int IN_BF16, int OUT_FINAL>
__global__ __launch_bounds__(256) void mlp_gemm(
    const void* __restrict__ in,
    const float* __restrict__ wts,    // [T][K][N]
    const float* __restrict__ bias,   // [T][N]
    void* __restrict__ out,
    const int* __restrict__ sidx,
    const int* __restrict__ tile_base,
    const int* __restrict__ tile_task,
    const int* __restrict__ tile_end,
    const int* __restrict__ ntiles)
{
    const int tile = blockIdx.y;
    if (tile >= *ntiles) return;
    const int rowbase = tile_base[tile];
    const int task    = tile_task[tile];
    const int rowend  = tile_end[tile];
    const int n0      = blockIdx.x * BN;

    __shared__ __align__(16) short Als[BM * BK];   // 16 KB, [m][k] swizzled
    __shared__ __align__(16) short Bls[BN * BK];   // 16 KB, [n][k] swizzled (W^T)

    const int tid  = threadIdx.x;
    const int lane = tid & 63;
    const int wid  = tid >> 6;
    const int wm   = wid >> 1;   // 0..1 : 64-row half
    const int wn   = wid & 1;    // 0..1 : 64-col half

    f32x4 acc[4][4];
    #pragma unroll
    for (int mf = 0; mf < 4; ++mf)
        #pragma unroll
        for (int nf = 0; nf < 4; ++nf)
            acc[mf][nf] = (f32x4){0.f, 0.f, 0.f, 0.f};

    const float* W = wts + (size_t)task * K * N;

    for (int kt = 0; kt < K; kt += BK) {
        // ---- stage A tile: 128 rows x 64 k (bf16, swizzled) ----
        {
            int m0 = tid >> 3;        // 0..31
            int cw = tid & 7;         // k-chunk of 8
            #pragma unroll
            for (int p = 0; p < 4; ++p) {
                int m = m0 + 32 * p;
                int grow = rowbase + m;
                if (grow > B_ROWS - 1) grow = B_ROWS - 1;
                int lidx = (m * 8 + (cw ^ (m & 7))) * 8;   // element index
                if (IN_BF16) {
                    const unsigned short* src =
                        (const unsigned short*)in + (size_t)grow * K + kt + cw * 8;
                    *(bf16x8*)&Als[lidx] = *(const bf16x8*)src;
                } else {
                    const float* src =
                        (const float*)in + (size_t)sidx[grow] * K + kt + cw * 8;
                    f32x4 v0 = *(const f32x4*)src;
                    f32x4 v1 = *(const f32x4*)(src + 4);
                    bf16x8 pk;
                    pk[0] = f2bf(v0[0]); pk[1] = f2bf(v0[1]);
                    pk[2] = f2bf(v0[2]); pk[3] = f2bf(v0[3]);
                    pk[4] = f2bf(v1[0]); pk[5] = f2bf(v1[1]);
                    pk[6] = f2bf(v1[2]); pk[7] = f2bf(v1[3]);
                    *(bf16x8*)&Als[lidx] = pk;
                }
            }
        }
        // ---- stage B tile: W[kt..kt+63][n0..n0+127] -> Bls[n][k] (bf16) ----
        {
            int n  = tid & 127;       // LDS row (output col)
            int c0 = tid >> 7;        // 0..1
            #pragma unroll
            for (int i = 0; i < 4; ++i) {
                int cw = c0 + i * 2;  // k-chunk of 8
                const float* src = W + (size_t)(kt + cw * 8) * N + n0 + n;
                bf16x8 pk;
                #pragma unroll
                for (int j = 0; j < 8; ++j) pk[j] = f2bf(src[(size_t)j * N]);
                int lidx = (n * 8 + (cw ^ (n & 7))) * 8;
                *(bf16x8*)&Bls[lidx] = pk;
            }
        }
        __syncthreads();

        // ---- compute: 2 K-steps of 32, 16 MFMA each ----
        #pragma unroll
        for (int ks = 0; ks < 2; ++ks) {
            bf16x8 a[4], b[4];
            const int r16 = lane & 15;
            const int kc  = ks * 4 + (lane >> 4);   // k-chunk 0..7
            #pragma unroll
            for (int mf = 0; mf < 4; ++mf) {
                int row = wm * 64 + mf * 16 + r16;
                a[mf] = *(const bf16x8*)&Als[(row * 8 + (kc ^ (row & 7))) * 8];
            }
            #pragma unroll
            for (int nf = 0; nf < 4; ++nf) {
                int col = wn * 64 + nf * 16 + r16;
                b[nf] = *(const bf16x8*)&Bls[(col * 8 + (kc ^ (col & 7))) * 8];
            }
            #pragma unroll
            for (int mf = 0; mf < 4; ++mf)
                #pragma unroll
                for (int nf = 0; nf < 4; ++nf)
                    acc[mf][nf] = __builtin_amdgcn_mfma_f32_16x16x32_bf16(
                        a[mf], b[nf], acc[mf][nf], 0, 0, 0);
        }
        __syncthreads();
    }

    // ---- epilogue: bias (+tanh) and store ----
    {
        const int r16 = lane & 15;
        const int rg  = lane >> 4;
        #pragma unroll
        for (int nf = 0; nf < 4; ++nf) {
            const int col = n0 + wn * 64 + nf * 16 + r16;
            const float bv = bias[(size_t)task * N + col];
            #pragma unroll
            for (int mf = 0; mf < 4; ++mf) {
                #pragma unroll
                for (int r = 0; r < 4; ++r) {
                    int row_l = wm * 64 + mf * 16 + rg * 4 + r;
                    int grow = rowbase + row_l;
                    if (grow < rowend) {
                        float v = acc[mf][nf][r] + bv;
                        if (!OUT_FINAL) {
                            v = tanhf(v);
                            ((unsigned short*)out)[(size_t)grow * N + col] =
                                (unsigned short)f2bf(v);
                        } else {
                            ((float*)out)[(size_t)sidx[grow] * N + col] = v;
                        }
                    }
                }
            }
        }
    }
}

// ---------------------------------------------------------------------------
extern "C" void kernel_launch(void* const* d_in, const int* in_sizes, int n_in,
                              void* d_out, int out_size, void* d_ws, size_t ws_size,
                              hipStream_t stream)
{
    const float* x        = (const float*)d_in[0];
    const int*   task_ids = (const int*)  d_in[1];
    const float* k0       = (const float*)d_in[2];
    const float* b0       = (const float*)d_in[3];
    const float* k1       = (const float*)d_in[4];
    const float* b1       = (const float*)d_in[5];
    const float* k2       = (const float*)d_in[6];
    const float* b2       = (const float*)d_in[7];
    float* out = (float*)d_out;

    char* ws = (char*)d_ws;
    int* sidx      = (int*)ws;           // 8192 ints
    int* tile_base = sidx + 8192;        // up to 80, padded to 128
    int* tile_task = tile_base + 128;
    int* tile_end  = tile_task + 128;
    int* ntiles    = tile_end + 128;
    unsigned short* H0 = (unsigned short*)(ws + 65536);              // 8192x1024 bf16
    unsigned short* H1 = (unsigned short*)(ws + 65536 + 16777216);   // 8192x1024 bf16

    bucket_kernel<<<1, 256, 0, stream>>>(task_ids, sidx, tile_base, tile_task,
                                         tile_end, ntiles);

    // layer 0: x[8192,512] (fp32 gather) -> H0[8192,1024] bf16 tanh
    mlp_gemm<512, 1024, 0, 0><<<dim3(8, MAX_TILES), 256, 0, stream>>>(
        x, k0, b0, H0, sidx, tile_base, tile_task, tile_end, ntiles);

    // layer 1: H0 -> H1[8192,1024] bf16 tanh
    mlp_gemm<1024, 1024, 1, 0><<<dim3(8, MAX_TILES), 256, 0, stream>>>(
        H0, k1, b1, H1, sidx, tile_base, tile_task, tile_end, ntiles);

    // layer 2: H1 -> out[8192,256] fp32 scatter (+bias, no tanh)
    mlp_gemm<1024, 256, 1, 1><<<dim3(2, MAX_TILES), 256, 0, stream>>>(
        H1, k2, b2, out, sidx, tile_base, tile_task, tile_end, ntiles);
}

// Round 2
// 198.125 us; speedup vs baseline: 1.0527x; 1.0527x over previous
//
#include <hip/hip_runtime.h>
#include <math.h>

#define NUM_TASKS 16
#define B_ROWS    8192
#define BM        128
#define BN        128
#define BK        64
#define MAX_TILES (B_ROWS / BM + NUM_TASKS)   // 80

typedef __attribute__((ext_vector_type(4))) float f32x4;
typedef __attribute__((ext_vector_type(8))) short bf16x8;
typedef __attribute__((ext_vector_type(4))) short bf16x4;

__device__ __forceinline__ short f2bf(float f) {
    union { float f; unsigned u; } c; c.f = f;
    unsigned u = c.u;
    unsigned r = (u + 0x7FFFu + ((u >> 16) & 1u)) >> 16;
    return (short)r;
}

// async global->LDS, 16B per lane; LDS dest is wave-uniform base + lane*16
__device__ __forceinline__ void gld16(const void* g, void* l) {
    __builtin_amdgcn_global_load_lds(
        (const __attribute__((address_space(1))) unsigned int*)g,
        (__attribute__((address_space(3))) unsigned int*)l,
        16, 0, 0);
}

// ---------------------------------------------------------------------------
// Bucket kernel: deterministic (stable) counting sort of rows by task.
// ---------------------------------------------------------------------------
__global__ __launch_bounds__(256) void bucket_kernel(
    const int* __restrict__ task_ids,
    int* __restrict__ sidx,
    int* __restrict__ tile_base,
    int* __restrict__ tile_task,
    int* __restrict__ tile_end,
    int* __restrict__ ntiles)
{
    __shared__ int cnt[256][NUM_TASKS];
    __shared__ int offs[NUM_TASKS + 1];
    __shared__ int tot[NUM_TASKS];

    const int tid = threadIdx.x;
    #pragma unroll
    for (int t = 0; t < NUM_TASKS; ++t) cnt[tid][t] = 0;
    const int base = tid * (B_ROWS / 256);

    for (int i = 0; i < B_ROWS / 256; ++i) {
        int t = task_ids[base + i];
        cnt[tid][t]++;
    }
    __syncthreads();

    if (tid < NUM_TASKS) {
        int s = 0;
        for (int c = 0; c < 256; ++c) { int v = cnt[c][tid]; cnt[c][tid] = s; s += v; }
        tot[tid] = s;
    }
    __syncthreads();

    if (tid == 0) {
        int s = 0;
        for (int t = 0; t < NUM_TASKS; ++t) { offs[t] = s; s += tot[t]; }
        offs[NUM_TASKS] = s;
        int nt = 0;
        for (int t = 0; t < NUM_TASKS; ++t) {
            for (int r = offs[t]; r < offs[t + 1]; r += BM) {
                tile_base[nt] = r;
                tile_task[nt] = t;
                tile_end[nt]  = offs[t + 1];
                nt++;
            }
        }
        *ntiles = nt;
    }
    __syncthreads();

    for (int i = 0; i < B_ROWS / 256; ++i) {
        int row = base + i;
        int t = task_ids[row];
        int pos = offs[t] + cnt[tid][t];
        cnt[tid][t] = cnt[tid][t] + 1;
        sidx[pos] = row;
    }
}

// ---------------------------------------------------------------------------
// x gather+convert: xs[pos][c] = bf16(x[sidx[pos]][c]); 4 rows per block.
// ---------------------------------------------------------------------------
__global__ __launch_bounds__(256) void xconv(
    const float* __restrict__ x,
    const int* __restrict__ sidx,
    unsigned short* __restrict__ xs)
{
    const int tid  = threadIdx.x;
    const int lrow = tid >> 6;
    const int lane = tid & 63;
    const int pos  = blockIdx.x * 4 + lrow;
    const int src  = sidx[pos];
    const float* sp = x + (size_t)src * 512 + lane * 8;
    f32x4 v0 = *(const f32x4*)sp;
    f32x4 v1 = *(const f32x4*)(sp + 4);
    bf16x8 pk;
    pk[0] = f2bf(v0[0]); pk[1] = f2bf(v0[1]);
    pk[2] = f2bf(v0[2]); pk[3] = f2bf(v0[3]);
    pk[4] = f2bf(v1[0]); pk[5] = f2bf(v1[1]);
    pk[6] = f2bf(v1[2]); pk[7] = f2bf(v1[3]);
    *(bf16x8*)(xs + (size_t)pos * 512 + lane * 8) = pk;
}

// ---------------------------------------------------------------------------
// Weight convert + transpose: W[t][k][n] fp32 -> Wt[t][n][k] bf16.
// 64x64 tiles via LDS (pad 68 shorts: ~4-way write conflict, aligned 8B reads)
// ---------------------------------------------------------------------------
template<int K, int N>
__global__ __launch_bounds__(256) void wconv(
    const float* __restrict__ W, unsigned short* __restrict__ Wt)
{
    const int t  = blockIdx.z;
    const int kb = blockIdx.y * 64;
    const int nb = blockIdx.x * 64;
    const float* src = W + (size_t)t * K * N;
    unsigned short* dst = Wt + (size_t)t * N * K;

    __shared__ unsigned short tile[64][68];

    const int tid = threadIdx.x;
    {
        int kl  = tid >> 4;          // 0..15
        int nl4 = (tid & 15) * 4;    // 0..60
        #pragma unroll
        for (int r = 0; r < 4; ++r) {
            int k = kl + r * 16;
            f32x4 v = *(const f32x4*)(src + (size_t)(kb + k) * N + nb + nl4);
            tile[nl4 + 0][k] = (unsigned short)f2bf(v[0]);
            tile[nl4 + 1][k] = (unsigned short)f2bf(v[1]);
            tile[nl4 + 2][k] = (unsigned short)f2bf(v[2]);
            tile[nl4 + 3][k] = (unsigned short)f2bf(v[3]);
        }
    }
    __syncthreads();
    {
        int nl = tid >> 2;           // 0..63
        int c  = (tid & 3) * 16;     // 0,16,32,48
        bf16x4 v0 = *(const bf16x4*)&tile[nl][c + 0];
        bf16x4 v1 = *(const bf16x4*)&tile[nl][c + 4];
        bf16x4 v2 = *(const bf16x4*)&tile[nl][c + 8];
        bf16x4 v3 = *(const bf16x4*)&tile[nl][c + 12];
        unsigned short* dp = dst + (size_t)(nb + nl) * K + kb + c;
        *(bf16x4*)(dp + 0)  = v0;
        *(bf16x4*)(dp + 4)  = v1;
        *(bf16x4*)(dp + 8)  = v2;
        *(bf16x4*)(dp + 12) = v3;
    }
}

// ---------------------------------------------------------------------------
// Grouped GEMM layer. Inputs: in = sorted bf16 [rows][K]; Wt = bf16 [T][N][K].
// global_load_lds(16B) staging with pre-swizzled per-lane global source,
// linear LDS dest; XOR-swizzled ds_read_b128 fragment reads (0 conflicts).
//   OUT_FINAL=0 : out = bf16 tanh(acc+bias), stored sorted
//   OUT_FINAL=1 : out = fp32 (acc+bias), scattered via sidx
// ---------------------------------------------------------------------------
template<int K, int N, int OUT_FINAL>
__global__ __launch_bounds__(256) void mlp_gemm(
    const unsigned short* __restrict__ in,
    const unsigned short* __restrict__ wt,    // [T][N][K] bf16
    const float* __restrict__ bias,           // [T][N]
    void* __restrict__ out,
    const int* __restrict__ sidx,
    const int* __restrict__ tile_base,
    const int* __restrict__ tile_task,
    const int* __restrict__ tile_end,
    const int* __restrict__ ntiles)
{
    const int tile = blockIdx.y;
    if (tile >= *ntiles) return;
    const int rowbase = tile_base[tile];
    const int task    = tile_task[tile];
    const int rowend  = tile_end[tile];
    const int n0      = blockIdx.x * BN;

    __shared__ __align__(16) short Als[BM * BK];   // 16 KB
    __shared__ __align__(16) short Bls[BN * BK];   // 16 KB

    const int tid  = threadIdx.x;
    const int lane = tid & 63;
    const int wid  = tid >> 6;
    const int wm   = wid >> 1;
    const int wn   = wid & 1;

    f32x4 acc[4][4];
    #pragma unroll
    for (int mf = 0; mf < 4; ++mf)
        #pragma unroll
        for (int nf = 0; nf < 4; ++nf)
            acc[mf][nf] = (f32x4){0.f, 0.f, 0.f, 0.f};

    // ---- staging geometry: round r stages 2048 elems at LDS elem r*2048 ----
    // lane's element within round block: e0 = wid*512 + lane*8
    // LDS layout target: elem (row*64 + ((kc ^ (row&7))*8) + j); we write
    // linearly, so the global SOURCE is pre-swizzled per lane.
    const int e0   = wid * 512 + lane * 8;
    const int srow = e0 >> 6;            // 0..31 row within round group
    const int spos = (e0 >> 3) & 7;      // chunk slot in LDS
    const int kc0  = spos ^ (srow & 7);  // which k-chunk belongs in that slot

    const unsigned short* Wtt = wt + (size_t)task * N * K;

    const unsigned short* aptr[4];
    const unsigned short* bptr[4];
    short* alds[4];
    short* blds[4];
    #pragma unroll
    for (int r = 0; r < 4; ++r) {
        int row = r * 32 + srow;
        int ga = rowbase + row; if (ga > B_ROWS - 1) ga = B_ROWS - 1;
        aptr[r] = in  + (size_t)ga * K + kc0 * 8;
        bptr[r] = Wtt + (size_t)(n0 + row) * K + kc0 * 8;
        alds[r] = &Als[r * 2048 + wid * 512];   // wave-uniform
        blds[r] = &Bls[r * 2048 + wid * 512];
    }

    const int r16 = lane & 15;
    const int khi = lane >> 4;           // 0..3

    for (int kt = 0; kt < K; kt += BK) {
        #pragma unroll
        for (int r = 0; r < 4; ++r) {
            gld16(aptr[r], alds[r]);
            gld16(bptr[r], blds[r]);
            aptr[r] += BK;
            bptr[r] += BK;
        }
        __syncthreads();

        #pragma unroll
        for (int ks = 0; ks < 2; ++ks) {
            bf16x8 a[4], b[4];
            const int kc = ks * 4 + khi;
            #pragma unroll
            for (int mf = 0; mf < 4; ++mf) {
                int row = wm * 64 + mf * 16 + r16;
                a[mf] = *(const bf16x8*)&Als[row * 64 + (kc ^ (row & 7)) * 8];
            }
            #pragma unroll
            for (int nf = 0; nf < 4; ++nf) {
                int col = wn * 64 + nf * 16 + r16;
                b[nf] = *(const bf16x8*)&Bls[col * 64 + (kc ^ (col & 7)) * 8];
            }
            #pragma unroll
            for (int mf = 0; mf < 4; ++mf)
                #pragma unroll
                for (int nf = 0; nf < 4; ++nf)
                    acc[mf][nf] = __builtin_amdgcn_mfma_f32_16x16x32_bf16(
                        a[mf], b[nf], acc[mf][nf], 0, 0, 0);
        }
        __syncthreads();
    }

    // ---- epilogue ----
    {
        const int rg = lane >> 4;
        #pragma unroll
        for (int nf = 0; nf < 4; ++nf) {
            const int col = n0 + wn * 64 + nf * 16 + r16;
            const float bv = bias[(size_t)task * N + col];
            #pragma unroll
            for (int mf = 0; mf < 4; ++mf) {
                #pragma unroll
                for (int r = 0; r < 4; ++r) {
                    int row_l = wm * 64 + mf * 16 + rg * 4 + r;
                    int grow = rowbase + row_l;
                    if (grow < rowend) {
                        float v = acc[mf][nf][r] + bv;
                        if (!OUT_FINAL) {
                            v = tanhf(v);
                            ((unsigned short*)out)[(size_t)grow * N + col] =
                                (unsigned short)f2bf(v);
                        } else {
                            ((float*)out)[(size_t)sidx[grow] * N + col] = v;
                        }
                    }
                }
            }
        }
    }
}

// ---------------------------------------------------------------------------
extern "C" void kernel_launch(void* const* d_in, const int* in_sizes, int n_in,
                              void* d_out, int out_size, void* d_ws, size_t ws_size,
                              hipStream_t stream)
{
    const float* x        = (const float*)d_in[0];
    const int*   task_ids = (const int*)  d_in[1];
    const float* k0       = (const float*)d_in[2];
    const float* b0       = (const float*)d_in[3];
    const float* k1       = (const float*)d_in[4];
    const float* b1       = (const float*)d_in[5];
    const float* k2       = (const float*)d_in[6];
    const float* b2       = (const float*)d_in[7];
    float* out = (float*)d_out;

    char* ws = (char*)d_ws;
    int* sidx      = (int*)ws;
    int* tile_base = sidx + 8192;
    int* tile_task = tile_base + 128;
    int* tile_end  = tile_task + 128;
    int* ntiles    = tile_end + 128;

    size_t off = 65536;
    unsigned short* xs  = (unsigned short*)(ws + off); off += (size_t)8192 * 512 * 2;
    unsigned short* H0  = (unsigned short*)(ws + off); off += (size_t)8192 * 1024 * 2;
    unsigned short* H1  = (unsigned short*)(ws + off); off += (size_t)8192 * 1024 * 2;
    unsigned short* Wt0 = (unsigned short*)(ws + off); off += (size_t)16 * 512 * 1024 * 2;
    unsigned short* Wt1 = (unsigned short*)(ws + off); off += (size_t)16 * 1024 * 1024 * 2;
    unsigned short* Wt2 = (unsigned short*)(ws + off); off += (size_t)16 * 1024 * 256 * 2;

    bucket_kernel<<<1, 256, 0, stream>>>(task_ids, sidx, tile_base, tile_task,
                                         tile_end, ntiles);
    xconv<<<2048, 256, 0, stream>>>(x, sidx, xs);
    wconv< 512, 1024><<<dim3(16,  8, 16), 256, 0, stream>>>(k0, Wt0);
    wconv<1024, 1024><<<dim3(16, 16, 16), 256, 0, stream>>>(k1, Wt1);
    wconv<1024,  256><<<dim3( 4, 16, 16), 256, 0, stream>>>(k2, Wt2);

    mlp_gemm< 512, 1024, 0><<<dim3(8, MAX_TILES), 256, 0, stream>>>(
        xs, Wt0, b0, H0, sidx, tile_base, tile_task, tile_end, ntiles);
    mlp_gemm<1024, 1024, 0><<<dim3(8, MAX_TILES), 256, 0, stream>>>(
        H0, Wt1, b1, H1, sidx, tile_base, tile_task, tile_end, ntiles);
    mlp_gemm<1024,  256, 1><<<dim3(2, MAX_TILES), 256, 0, stream>>>(
        H1, Wt2, b2, out, sidx, tile_base, tile_task, tile_end, ntiles);
}

// Round 3
// 168.944 us; speedup vs baseline: 1.2345x; 1.1727x over previous
//
#include <hip/hip_runtime.h>
#include <math.h>

#define NUM_TASKS 16
#define B_ROWS    8192
#define BM        128
#define BK        64
#define MAX_TILES (B_ROWS / BM + NUM_TASKS)   // 80

typedef __attribute__((ext_vector_type(4))) float f32x4;
typedef __attribute__((ext_vector_type(8))) short bf16x8;
typedef __attribute__((ext_vector_type(4))) short bf16x4;

__device__ __forceinline__ short f2bf(float f) {
    union { float f; unsigned u; } c; c.f = f;
    unsigned u = c.u;
    unsigned r = (u + 0x7FFFu + ((u >> 16) & 1u)) >> 16;
    return (short)r;
}

__device__ __forceinline__ void gld16(const void* g, void* l) {
    __builtin_amdgcn_global_load_lds(
        (const __attribute__((address_space(1))) unsigned int*)g,
        (__attribute__((address_space(3))) unsigned int*)l,
        16, 0, 0);
}

// ---------------------------------------------------------------------------
// Bucket kernel: deterministic (stable) counting sort of rows by task.
// ---------------------------------------------------------------------------
__global__ __launch_bounds__(256) void bucket_kernel(
    const int* __restrict__ task_ids,
    int* __restrict__ sidx,
    int* __restrict__ tile_base,
    int* __restrict__ tile_task,
    int* __restrict__ tile_end,
    int* __restrict__ ntiles)
{
    __shared__ int cnt[256][NUM_TASKS];
    __shared__ int offs[NUM_TASKS + 1];
    __shared__ int tot[NUM_TASKS];

    const int tid = threadIdx.x;
    #pragma unroll
    for (int t = 0; t < NUM_TASKS; ++t) cnt[tid][t] = 0;
    const int base = tid * (B_ROWS / 256);

    for (int i = 0; i < B_ROWS / 256; ++i) {
        int t = task_ids[base + i];
        cnt[tid][t]++;
    }
    __syncthreads();

    if (tid < NUM_TASKS) {
        int s = 0;
        for (int c = 0; c < 256; ++c) { int v = cnt[c][tid]; cnt[c][tid] = s; s += v; }
        tot[tid] = s;
    }
    __syncthreads();

    if (tid == 0) {
        int s = 0;
        for (int t = 0; t < NUM_TASKS; ++t) { offs[t] = s; s += tot[t]; }
        offs[NUM_TASKS] = s;
        int nt = 0;
        for (int t = 0; t < NUM_TASKS; ++t) {
            for (int r = offs[t]; r < offs[t + 1]; r += BM) {
                tile_base[nt] = r;
                tile_task[nt] = t;
                tile_end[nt]  = offs[t + 1];
                nt++;
            }
        }
        *ntiles = nt;
    }
    __syncthreads();

    for (int i = 0; i < B_ROWS / 256; ++i) {
        int row = base + i;
        int t = task_ids[row];
        int pos = offs[t] + cnt[tid][t];
        cnt[tid][t] = cnt[tid][t] + 1;
        sidx[pos] = row;
    }
}

// ---------------------------------------------------------------------------
// x gather+convert: xs[pos][c] = bf16(x[sidx[pos]][c]); 4 rows per block.
// ---------------------------------------------------------------------------
__global__ __launch_bounds__(256) void xconv(
    const float* __restrict__ x,
    const int* __restrict__ sidx,
    unsigned short* __restrict__ xs)
{
    const int tid  = threadIdx.x;
    const int lrow = tid >> 6;
    const int lane = tid & 63;
    const int pos  = blockIdx.x * 4 + lrow;
    const int src  = sidx[pos];
    const float* sp = x + (size_t)src * 512 + lane * 8;
    f32x4 v0 = *(const f32x4*)sp;
    f32x4 v1 = *(const f32x4*)(sp + 4);
    bf16x8 pk;
    pk[0] = f2bf(v0[0]); pk[1] = f2bf(v0[1]);
    pk[2] = f2bf(v0[2]); pk[3] = f2bf(v0[3]);
    pk[4] = f2bf(v1[0]); pk[5] = f2bf(v1[1]);
    pk[6] = f2bf(v1[2]); pk[7] = f2bf(v1[3]);
    *(bf16x8*)(xs + (size_t)pos * 512 + lane * 8) = pk;
}

// ---------------------------------------------------------------------------
// Weight convert + transpose: W[t][k][n] fp32 -> Wt[t][n][k] bf16.
// ---------------------------------------------------------------------------
template<int K, int N>
__global__ __launch_bounds__(256) void wconv(
    const float* __restrict__ W, unsigned short* __restrict__ Wt)
{
    const int t  = blockIdx.z;
    const int kb = blockIdx.y * 64;
    const int nb = blockIdx.x * 64;
    const float* src = W + (size_t)t * K * N;
    unsigned short* dst = Wt + (size_t)t * N * K;

    __shared__ unsigned short tile[64][68];

    const int tid = threadIdx.x;
    {
        int kl  = tid >> 4;
        int nl4 = (tid & 15) * 4;
        #pragma unroll
        for (int r = 0; r < 4; ++r) {
            int k = kl + r * 16;
            f32x4 v = *(const f32x4*)(src + (size_t)(kb + k) * N + nb + nl4);
            tile[nl4 + 0][k] = (unsigned short)f2bf(v[0]);
            tile[nl4 + 1][k] = (unsigned short)f2bf(v[1]);
            tile[nl4 + 2][k] = (unsigned short)f2bf(v[2]);
            tile[nl4 + 3][k] = (unsigned short)f2bf(v[3]);
        }
    }
    __syncthreads();
    {
        int nl = tid >> 2;
        int c  = (tid & 3) * 16;
        bf16x4 v0 = *(const bf16x4*)&tile[nl][c + 0];
        bf16x4 v1 = *(const bf16x4*)&tile[nl][c + 4];
        bf16x4 v2 = *(const bf16x4*)&tile[nl][c + 8];
        bf16x4 v3 = *(const bf16x4*)&tile[nl][c + 12];
        unsigned short* dp = dst + (size_t)(nb + nl) * K + kb + c;
        *(bf16x4*)(dp + 0)  = v0;
        *(bf16x4*)(dp + 4)  = v1;
        *(bf16x4*)(dp + 8)  = v2;
        *(bf16x4*)(dp + 12) = v3;
    }
}

// ---------------------------------------------------------------------------
// Grouped GEMM layer, 2-phase double-buffered pipeline with counted vmcnt.
//   in  : sorted bf16 [rows][K]
//   wt  : bf16 [T][N][K]
// BM=128, BK=64, BN_ template (128 or 64). 4 waves (2x2).
// Per iteration: stage(t+1 -> buf^1), vmcnt(NLOADS) [oldest batch done],
// raw s_barrier (no drain), ds_read+MFMA on buf, raw s_barrier.
// ---------------------------------------------------------------------------
template<int K, int N, int BN_, int OUT_FINAL>
__global__ __launch_bounds__(256, 2) void mlp_gemm(
    const unsigned short* __restrict__ in,
    const unsigned short* __restrict__ wt,
    const float* __restrict__ bias,
    void* __restrict__ out,
    const int* __restrict__ sidx,
    const int* __restrict__ tile_base,
    const int* __restrict__ tile_task,
    const int* __restrict__ tile_end,
    const int* __restrict__ ntiles)
{
    constexpr int NBLKN   = N / BN_;
    constexpr int NB      = NBLKN * MAX_TILES;
    constexpr int NT      = K / BK;
    constexpr int BROUNDS = (BN_ * BK) / 2048;     // 4 (BN=128) or 2 (BN=64)
    constexpr int NLOADS  = 4 + BROUNDS;
    constexpr int NF      = BN_ / 32;
    constexpr int LDSE    = (BM + BN_) * BK;       // elems per buffer

    // bijective XCD swizzle (m204)
    const int orig = blockIdx.x;
    constexpr int q = NB / 8, rr = NB % 8;
    const int xcd = orig & 7, idx = orig >> 3;
    const int wgid = (xcd < rr ? xcd * (q + 1) : rr * (q + 1) + (xcd - rr) * q) + idx;
    const int tile = wgid / NBLKN;
    const int n0   = (wgid % NBLKN) * BN_;

    if (tile >= *ntiles) return;
    const int rowbase = tile_base[tile];
    const int task    = tile_task[tile];
    const int rowend  = tile_end[tile];

    __shared__ __align__(16) short LDSb[2][LDSE];

    const int tid  = threadIdx.x;
    const int lane = tid & 63;
    const int wid  = tid >> 6;
    const int wm   = wid >> 1;
    const int wn   = wid & 1;

    f32x4 acc[4][NF];
    #pragma unroll
    for (int mf = 0; mf < 4; ++mf)
        #pragma unroll
        for (int nf = 0; nf < NF; ++nf)
            acc[mf][nf] = (f32x4){0.f, 0.f, 0.f, 0.f};

    // staging geometry: pre-swizzled global source, linear LDS dest
    const int e0   = wid * 512 + lane * 8;
    const int srow = e0 >> 6;            // row within 32-row round group
    const int spos = (e0 >> 3) & 7;      // chunk slot in LDS row
    const int kc0  = spos ^ (srow & 7);  // k-chunk that belongs in that slot

    const unsigned short* Wtt = wt + (size_t)task * N * K;

    const unsigned short* aglob[4];
    const unsigned short* bglob[BROUNDS];
    #pragma unroll
    for (int r = 0; r < 4; ++r) {
        int ga = rowbase + r * 32 + srow;
        if (ga > B_ROWS - 1) ga = B_ROWS - 1;
        aglob[r] = in + (size_t)ga * K + kc0 * 8;
    }
    #pragma unroll
    for (int r = 0; r < BROUNDS; ++r)
        bglob[r] = Wtt + (size_t)(n0 + r * 32 + srow) * K + kc0 * 8;

    const int r16 = lane & 15;
    const int khi = lane >> 4;

    // prologue: stage tile 0 into buf 0
    {
        short* Ab = &LDSb[0][0] + wid * 512;
        short* Bb = &LDSb[0][BM * BK] + wid * 512;
        #pragma unroll
        for (int r = 0; r < 4; ++r)       gld16(aglob[r], Ab + r * 2048);
        #pragma unroll
        for (int r = 0; r < BROUNDS; ++r) gld16(bglob[r], Bb + r * 2048);
    }

    #pragma unroll 2
    for (int t = 0; t < NT; ++t) {
        const int cur = t & 1;
        if (t + 1 < NT) {
            const size_t ke = (size_t)(t + 1) * BK;
            short* Ab = &LDSb[cur ^ 1][0] + wid * 512;
            short* Bb = &LDSb[cur ^ 1][BM * BK] + wid * 512;
            #pragma unroll
            for (int r = 0; r < 4; ++r)       gld16(aglob[r] + ke, Ab + r * 2048);
            #pragma unroll
            for (int r = 0; r < BROUNDS; ++r) gld16(bglob[r] + ke, Bb + r * 2048);
            asm volatile("s_waitcnt vmcnt(%0)" :: "n"(NLOADS) : "memory");
        } else {
            asm volatile("s_waitcnt vmcnt(0)" ::: "memory");
        }
        asm volatile("s_barrier" ::: "memory");

        const short* Abase = &LDSb[cur][0];
        const short* Bbase = &LDSb[cur][BM * BK];
        #pragma unroll
        for (int ks = 0; ks < 2; ++ks) {
            bf16x8 a[4], b[NF];
            const int kc = ks * 4 + khi;
            #pragma unroll
            for (int mf = 0; mf < 4; ++mf) {
                int row = wm * 64 + mf * 16 + r16;
                a[mf] = *(const bf16x8*)&Abase[row * 64 + (kc ^ (row & 7)) * 8];
            }
            #pragma unroll
            for (int nf = 0; nf < NF; ++nf) {
                int col = wn * (BN_ / 2) + nf * 16 + r16;
                b[nf] = *(const bf16x8*)&Bbase[col * 64 + (kc ^ (col & 7)) * 8];
            }
            #pragma unroll
            for (int mf = 0; mf < 4; ++mf)
                #pragma unroll
                for (int nf = 0; nf < NF; ++nf)
                    acc[mf][nf] = __builtin_amdgcn_mfma_f32_16x16x32_bf16(
                        a[mf], b[nf], acc[mf][nf], 0, 0, 0);
        }
        asm volatile("s_barrier" ::: "memory");
    }

    // ---- epilogue ----
    {
        const int rg = lane >> 4;
        #pragma unroll
        for (int nf = 0; nf < NF; ++nf) {
            const int col = n0 + wn * (BN_ / 2) + nf * 16 + r16;
            const float bv = bias[(size_t)task * N + col];
            #pragma unroll
            for (int mf = 0; mf < 4; ++mf) {
                #pragma unroll
                for (int r = 0; r < 4; ++r) {
                    int row_l = wm * 64 + mf * 16 + rg * 4 + r;
                    int grow = rowbase + row_l;
                    if (grow < rowend) {
                        float v = acc[mf][nf][r] + bv;
                        if (!OUT_FINAL) {
                            v = tanhf(v);
                            ((unsigned short*)out)[(size_t)grow * N + col] =
                                (unsigned short)f2bf(v);
                        } else {
                            ((float*)out)[(size_t)sidx[grow] * N + col] = v;
                        }
                    }
                }
            }
        }
    }
}

// ---------------------------------------------------------------------------
extern "C" void kernel_launch(void* const* d_in, const int* in_sizes, int n_in,
                              void* d_out, int out_size, void* d_ws, size_t ws_size,
                              hipStream_t stream)
{
    const float* x        = (const float*)d_in[0];
    const int*   task_ids = (const int*)  d_in[1];
    const float* k0       = (const float*)d_in[2];
    const float* b0       = (const float*)d_in[3];
    const float* k1       = (const float*)d_in[4];
    const float* b1       = (const float*)d_in[5];
    const float* k2       = (const float*)d_in[6];
    const float* b2       = (const float*)d_in[7];
    float* out = (float*)d_out;

    char* ws = (char*)d_ws;
    int* sidx      = (int*)ws;
    int* tile_base = sidx + 8192;
    int* tile_task = tile_base + 128;
    int* tile_end  = tile_task + 128;
    int* ntiles    = tile_end + 128;

    size_t off = 65536;
    unsigned short* xs  = (unsigned short*)(ws + off); off += (size_t)8192 * 512 * 2;
    unsigned short* H0  = (unsigned short*)(ws + off); off += (size_t)8192 * 1024 * 2;
    unsigned short* H1  = (unsigned short*)(ws + off); off += (size_t)8192 * 1024 * 2;
    unsigned short* Wt0 = (unsigned short*)(ws + off); off += (size_t)16 * 512 * 1024 * 2;
    unsigned short* Wt1 = (unsigned short*)(ws + off); off += (size_t)16 * 1024 * 1024 * 2;
    unsigned short* Wt2 = (unsigned short*)(ws + off); off += (size_t)16 * 1024 * 256 * 2;

    bucket_kernel<<<1, 256, 0, stream>>>(task_ids, sidx, tile_base, tile_task,
                                         tile_end, ntiles);
    xconv<<<2048, 256, 0, stream>>>(x, sidx, xs);
    wconv< 512, 1024><<<dim3(16,  8, 16), 256, 0, stream>>>(k0, Wt0);
    wconv<1024, 1024><<<dim3(16, 16, 16), 256, 0, stream>>>(k1, Wt1);
    wconv<1024,  256><<<dim3( 4, 16, 16), 256, 0, stream>>>(k2, Wt2);

    mlp_gemm< 512, 1024, 128, 0><<<8 * MAX_TILES, 256, 0, stream>>>(
        xs, Wt0, b0, H0, sidx, tile_base, tile_task, tile_end, ntiles);
    mlp_gemm<1024, 1024, 128, 0><<<8 * MAX_TILES, 256, 0, stream>>>(
        H0, Wt1, b1, H1, sidx, tile_base, tile_task, tile_end, ntiles);
    mlp_gemm<1024,  256,  64, 1><<<4 * MAX_TILES, 256, 0, stream>>>(
        H1, Wt2, b2, out, sidx, tile_base, tile_task, tile_end, ntiles);
}

// Round 4
// 155.700 us; speedup vs baseline: 1.3396x; 1.0851x over previous
//
#include <hip/hip_runtime.h>
#include <math.h>

#define NUM_TASKS 16
#define B_ROWS    8192
#define BM        128
#define BK        64
#define MAX_TILES (B_ROWS / BM + NUM_TASKS)   // 80

typedef __attribute__((ext_vector_type(4))) float f32x4;
typedef __attribute__((ext_vector_type(8))) short bf16x8;
typedef __attribute__((ext_vector_type(4))) short bf16x4;
typedef unsigned short ushort_t;

__device__ __forceinline__ short f2bf(float f) {
    union { float f; unsigned u; } c; c.f = f;
    unsigned u = c.u;
    unsigned r = (u + 0x7FFFu + ((u >> 16) & 1u)) >> 16;
    return (short)r;
}

__device__ __forceinline__ void gld16(const void* g, void* l) {
    __builtin_amdgcn_global_load_lds(
        (const __attribute__((address_space(1))) unsigned int*)g,
        (__attribute__((address_space(3))) unsigned int*)l,
        16, 0, 0);
}

// ---------------------------------------------------------------------------
// Bucket kernel: deterministic (stable) counting sort of rows by task.
// ---------------------------------------------------------------------------
__global__ __launch_bounds__(256) void bucket_kernel(
    const int* __restrict__ task_ids,
    int* __restrict__ sidx,
    int* __restrict__ tile_base,
    int* __restrict__ tile_task,
    int* __restrict__ tile_end,
    int* __restrict__ ntiles)
{
    __shared__ int cnt[256][NUM_TASKS];
    __shared__ int offs[NUM_TASKS + 1];
    __shared__ int tot[NUM_TASKS];

    const int tid = threadIdx.x;
    #pragma unroll
    for (int t = 0; t < NUM_TASKS; ++t) cnt[tid][t] = 0;
    const int base = tid * (B_ROWS / 256);

    for (int i = 0; i < B_ROWS / 256; ++i) {
        int t = task_ids[base + i];
        cnt[tid][t]++;
    }
    __syncthreads();

    if (tid < NUM_TASKS) {
        int s = 0;
        for (int c = 0; c < 256; ++c) { int v = cnt[c][tid]; cnt[c][tid] = s; s += v; }
        tot[tid] = s;
    }
    __syncthreads();

    if (tid == 0) {
        int s = 0;
        for (int t = 0; t < NUM_TASKS; ++t) { offs[t] = s; s += tot[t]; }
        offs[NUM_TASKS] = s;
        int nt = 0;
        for (int t = 0; t < NUM_TASKS; ++t) {
            for (int r = offs[t]; r < offs[t + 1]; r += BM) {
                tile_base[nt] = r;
                tile_task[nt] = t;
                tile_end[nt]  = offs[t + 1];
                nt++;
            }
        }
        *ntiles = nt;
    }
    __syncthreads();

    for (int i = 0; i < B_ROWS / 256; ++i) {
        int row = base + i;
        int t = task_ids[row];
        int pos = offs[t] + cnt[tid][t];
        cnt[tid][t] = cnt[tid][t] + 1;
        sidx[pos] = row;
    }
}

// ---------------------------------------------------------------------------
// x gather+convert: xs[pos][c] = bf16(x[sidx[pos]][c]); 4 rows per block.
// ---------------------------------------------------------------------------
__global__ __launch_bounds__(256) void xconv(
    const float* __restrict__ x,
    const int* __restrict__ sidx,
    ushort_t* __restrict__ xs)
{
    const int tid  = threadIdx.x;
    const int lrow = tid >> 6;
    const int lane = tid & 63;
    const int pos  = blockIdx.x * 4 + lrow;
    const int src  = sidx[pos];
    const float* sp = x + (size_t)src * 512 + lane * 8;
    f32x4 v0 = *(const f32x4*)sp;
    f32x4 v1 = *(const f32x4*)(sp + 4);
    bf16x8 pk;
    pk[0] = f2bf(v0[0]); pk[1] = f2bf(v0[1]);
    pk[2] = f2bf(v0[2]); pk[3] = f2bf(v0[3]);
    pk[4] = f2bf(v1[0]); pk[5] = f2bf(v1[1]);
    pk[6] = f2bf(v1[2]); pk[7] = f2bf(v1[3]);
    *(bf16x8*)(xs + (size_t)pos * 512 + lane * 8) = pk;
}

// ---------------------------------------------------------------------------
// Weight convert + transpose: W[t][k][n] fp32 -> Wt[t][n][k] bf16.
// ---------------------------------------------------------------------------
template<int K, int N>
__global__ __launch_bounds__(256) void wconv(
    const float* __restrict__ W, ushort_t* __restrict__ Wt)
{
    const int t  = blockIdx.z;
    const int kb = blockIdx.y * 64;
    const int nb = blockIdx.x * 64;
    const float* src = W + (size_t)t * K * N;
    ushort_t* dst = Wt + (size_t)t * N * K;

    __shared__ ushort_t tile[64][68];

    const int tid = threadIdx.x;
    {
        int kl  = tid >> 4;
        int nl4 = (tid & 15) * 4;
        #pragma unroll
        for (int r = 0; r < 4; ++r) {
            int k = kl + r * 16;
            f32x4 v = *(const f32x4*)(src + (size_t)(kb + k) * N + nb + nl4);
            tile[nl4 + 0][k] = (ushort_t)f2bf(v[0]);
            tile[nl4 + 1][k] = (ushort_t)f2bf(v[1]);
            tile[nl4 + 2][k] = (ushort_t)f2bf(v[2]);
            tile[nl4 + 3][k] = (ushort_t)f2bf(v[3]);
        }
    }
    __syncthreads();
    {
        int nl = tid >> 2;
        int c  = (tid & 3) * 16;
        bf16x4 v0 = *(const bf16x4*)&tile[nl][c + 0];
        bf16x4 v1 = *(const bf16x4*)&tile[nl][c + 4];
        bf16x4 v2 = *(const bf16x4*)&tile[nl][c + 8];
        bf16x4 v3 = *(const bf16x4*)&tile[nl][c + 12];
        ushort_t* dp = dst + (size_t)(nb + nl) * K + kb + c;
        *(bf16x4*)(dp + 0)  = v0;
        *(bf16x4*)(dp + 4)  = v1;
        *(bf16x4*)(dp + 8)  = v2;
        *(bf16x4*)(dp + 12) = v3;
    }
}

// ---------------------------------------------------------------------------
// Grouped GEMM layer: BM=128 x BN_=64, BK=64, 4 waves (2x2, wave-tile 64x32).
// Triple-buffered LDS (3 x 24KB), prefetch distance 2, counted vmcnt:
//   steady state: issue batch t+2 (6 gld16), s_waitcnt vmcnt(12) -> batch t
//   done (per-wave FIFO), raw s_barrier, ds_read+MFMA on buf t%3, s_barrier.
// K-loop fully unrolled (NT constexpr) so buffer index & waits are static.
// ---------------------------------------------------------------------------
template<int K, int N, int OUT_FINAL>
__global__ __launch_bounds__(256, 2) void mlp_gemm(
    const ushort_t* __restrict__ in,
    const ushort_t* __restrict__ wt,      // [T][N][K] bf16
    const float* __restrict__ bias,
    void* __restrict__ out,
    const int* __restrict__ sidx,
    const int* __restrict__ tile_base,
    const int* __restrict__ tile_task,
    const int* __restrict__ tile_end,
    const int* __restrict__ ntiles)
{
    constexpr int BN_     = 64;
    constexpr int NBLKN   = N / BN_;
    constexpr int NB      = NBLKN * MAX_TILES;
    constexpr int NT      = K / BK;
    constexpr int AROUNDS = 4;                     // 128*64 elems / 2048
    constexpr int BROUNDS = (BN_ * BK) / 2048;     // 2
    constexpr int BATCH   = AROUNDS + BROUNDS;     // 6
    constexpr int NF      = BN_ / 32;              // 2
    constexpr int LDSE    = (BM + BN_) * BK;       // 12288 elems / buffer

    // bijective XCD swizzle (m204)
    const int orig = blockIdx.x;
    constexpr int q = NB / 8, rr = NB % 8;
    const int xcd = orig & 7, idx = orig >> 3;
    const int wgid = (xcd < rr ? xcd * (q + 1) : rr * (q + 1) + (xcd - rr) * q) + idx;
    const int tile = wgid / NBLKN;
    const int n0   = (wgid % NBLKN) * BN_;

    if (tile >= *ntiles) return;
    const int rowbase = tile_base[tile];
    const int task    = tile_task[tile];
    const int rowend  = tile_end[tile];

    __shared__ __align__(16) short LDSb[3][LDSE];  // 72 KB

    const int tid  = threadIdx.x;
    const int lane = tid & 63;
    const int wid  = tid >> 6;
    const int wm   = wid >> 1;
    const int wn   = wid & 1;

    f32x4 acc[4][NF];
    #pragma unroll
    for (int mf = 0; mf < 4; ++mf)
        #pragma unroll
        for (int nf = 0; nf < NF; ++nf)
            acc[mf][nf] = (f32x4){0.f, 0.f, 0.f, 0.f};

    // staging geometry: pre-swizzled global source, linear LDS dest
    const int e0   = wid * 512 + lane * 8;
    const int srow = e0 >> 6;
    const int spos = (e0 >> 3) & 7;
    const int kc0  = spos ^ (srow & 7);

    const ushort_t* Wtt = wt + (size_t)task * N * K;

    const ushort_t* aglob[AROUNDS];
    const ushort_t* bglob[BROUNDS];
    #pragma unroll
    for (int r = 0; r < AROUNDS; ++r) {
        int ga = rowbase + r * 32 + srow;
        if (ga > B_ROWS - 1) ga = B_ROWS - 1;
        aglob[r] = in + (size_t)ga * K + kc0 * 8;
    }
    #pragma unroll
    for (int r = 0; r < BROUNDS; ++r)
        bglob[r] = Wtt + (size_t)(n0 + r * 32 + srow) * K + kc0 * 8;

    const int r16 = lane & 15;
    const int khi = lane >> 4;

    // prologue: stage batches 0 and 1
    #pragma unroll
    for (int p = 0; p < 2; ++p) {
        short* Ab = &LDSb[p][0] + wid * 512;
        short* Bb = &LDSb[p][BM * BK] + wid * 512;
        const size_t ke = (size_t)p * BK;
        #pragma unroll
        for (int r = 0; r < AROUNDS; ++r) gld16(aglob[r] + ke, Ab + r * 2048);
        #pragma unroll
        for (int r = 0; r < BROUNDS; ++r) gld16(bglob[r] + ke, Bb + r * 2048);
    }

    #pragma unroll
    for (int t = 0; t < NT; ++t) {
        if (t + 2 < NT) {
            const int nb_ = (t + 2) % 3;
            short* Ab = &LDSb[nb_][0] + wid * 512;
            short* Bb = &LDSb[nb_][BM * BK] + wid * 512;
            const size_t ke = (size_t)(t + 2) * BK;
            #pragma unroll
            for (int r = 0; r < AROUNDS; ++r) gld16(aglob[r] + ke, Ab + r * 2048);
            #pragma unroll
            for (int r = 0; r < BROUNDS; ++r) gld16(bglob[r] + ke, Bb + r * 2048);
            asm volatile("s_waitcnt vmcnt(%0)" :: "n"(2 * BATCH) : "memory");
        } else if (t + 2 == NT) {
            asm volatile("s_waitcnt vmcnt(%0)" :: "n"(BATCH) : "memory");
        } else {
            asm volatile("s_waitcnt vmcnt(0)" ::: "memory");
        }
        asm volatile("s_barrier" ::: "memory");

        const short* Abase = &LDSb[t % 3][0];
        const short* Bbase = &LDSb[t % 3][BM * BK];
        #pragma unroll
        for (int ks = 0; ks < 2; ++ks) {
            bf16x8 a[4], b[NF];
            const int kc = ks * 4 + khi;
            #pragma unroll
            for (int mf = 0; mf < 4; ++mf) {
                int row = wm * 64 + mf * 16 + r16;
                a[mf] = *(const bf16x8*)&Abase[row * 64 + (kc ^ (row & 7)) * 8];
            }
            #pragma unroll
            for (int nf = 0; nf < NF; ++nf) {
                int col = wn * 32 + nf * 16 + r16;
                b[nf] = *(const bf16x8*)&Bbase[col * 64 + (kc ^ (col & 7)) * 8];
            }
            #pragma unroll
            for (int mf = 0; mf < 4; ++mf)
                #pragma unroll
                for (int nf = 0; nf < NF; ++nf)
                    acc[mf][nf] = __builtin_amdgcn_mfma_f32_16x16x32_bf16(
                        a[mf], b[nf], acc[mf][nf], 0, 0, 0);
        }
        asm volatile("s_barrier" ::: "memory");
    }

    // ---- epilogue ----
    {
        const int rg = lane >> 4;
        #pragma unroll
        for (int nf = 0; nf < NF; ++nf) {
            const int col = n0 + wn * 32 + nf * 16 + r16;
            const float bv = bias[(size_t)task * N + col];
            #pragma unroll
            for (int mf = 0; mf < 4; ++mf) {
                #pragma unroll
                for (int r = 0; r < 4; ++r) {
                    int row_l = wm * 64 + mf * 16 + rg * 4 + r;
                    int grow = rowbase + row_l;
                    if (grow < rowend) {
                        float v = acc[mf][nf][r] + bv;
                        if (!OUT_FINAL) {
                            v = tanhf(v);
                            ((ushort_t*)out)[(size_t)grow * N + col] =
                                (ushort_t)f2bf(v);
                        } else {
                            ((float*)out)[(size_t)sidx[grow] * N + col] = v;
                        }
                    }
                }
            }
        }
    }
}

// ---------------------------------------------------------------------------
extern "C" void kernel_launch(void* const* d_in, const int* in_sizes, int n_in,
                              void* d_out, int out_size, void* d_ws, size_t ws_size,
                              hipStream_t stream)
{
    const float* x        = (const float*)d_in[0];
    const int*   task_ids = (const int*)  d_in[1];
    const float* k0       = (const float*)d_in[2];
    const float* b0       = (const float*)d_in[3];
    const float* k1       = (const float*)d_in[4];
    const float* b1       = (const float*)d_in[5];
    const float* k2       = (const float*)d_in[6];
    const float* b2       = (const float*)d_in[7];
    float* out = (float*)d_out;

    char* ws = (char*)d_ws;
    int* sidx      = (int*)ws;
    int* tile_base = sidx + 8192;
    int* tile_task = tile_base + 128;
    int* tile_end  = tile_task + 128;
    int* ntiles    = tile_end + 128;

    size_t off = 65536;
    ushort_t* xs  = (ushort_t*)(ws + off); off += (size_t)8192 * 512 * 2;
    ushort_t* H0  = (ushort_t*)(ws + off); off += (size_t)8192 * 1024 * 2;
    ushort_t* H1  = (ushort_t*)(ws + off); off += (size_t)8192 * 1024 * 2;
    ushort_t* Wt0 = (ushort_t*)(ws + off); off += (size_t)16 * 512 * 1024 * 2;
    ushort_t* Wt1 = (ushort_t*)(ws + off); off += (size_t)16 * 1024 * 1024 * 2;
    ushort_t* Wt2 = (ushort_t*)(ws + off); off += (size_t)16 * 1024 * 256 * 2;

    bucket_kernel<<<1, 256, 0, stream>>>(task_ids, sidx, tile_base, tile_task,
                                         tile_end, ntiles);
    xconv<<<2048, 256, 0, stream>>>(x, sidx, xs);
    wconv< 512, 1024><<<dim3(16,  8, 16), 256, 0, stream>>>(k0, Wt0);
    wconv<1024, 1024><<<dim3(16, 16, 16), 256, 0, stream>>>(k1, Wt1);
    wconv<1024,  256><<<dim3( 4, 16, 16), 256, 0, stream>>>(k2, Wt2);

    mlp_gemm< 512, 1024, 0><<<16 * MAX_TILES, 256, 0, stream>>>(
        xs, Wt0, b0, H0, sidx, tile_base, tile_task, tile_end, ntiles);
    mlp_gemm<1024, 1024, 0><<<16 * MAX_TILES, 256, 0, stream>>>(
        H0, Wt1, b1, H1, sidx, tile_base, tile_task, tile_end, ntiles);
    mlp_gemm<1024,  256, 1><<< 4 * MAX_TILES, 256, 0, stream>>>(
        H1, Wt2, b2, out, sidx, tile_base, tile_task, tile_end, ntiles);
}